// Round 1
// baseline (325.537 us; speedup 1.0000x reference)
//
#include <hip/hip_runtime.h>
#include <hip/hip_bf16.h>

#define B_ 4
#define C_ 256
#define N_ 4096
#define Dh 64

typedef __attribute__((ext_vector_type(8))) short short8;
typedef __attribute__((ext_vector_type(4))) float f32x4;

__device__ __forceinline__ ushort f2bf(float f) {
    union { float f; unsigned u; } v; v.f = f;
    unsigned u = v.u;
    return (ushort)((u + 0x7fffu + ((u >> 16) & 1u)) >> 16);
}

// ---- Kernel T: weights -> bf16, transposed (WT[d][c] = W[c][d]) ----
__global__ __launch_bounds__(256) void kT(const float* __restrict__ Wq,
                                          const float* __restrict__ Wk,
                                          const float* __restrict__ Wv,
                                          ushort* __restrict__ WqT,
                                          ushort* __restrict__ WkT,
                                          ushort* __restrict__ WvT) {
    int i = blockIdx.x * 256 + threadIdx.x;
    if (i < Dh * C_) {
        int d = i / C_, c = i % C_;
        WqT[i] = f2bf(Wq[c * Dh + d]);
        WkT[i] = f2bf(Wk[c * Dh + d]);
    }
    if (i < C_ * C_) {
        int d = i / C_, c = i % C_;
        WvT[i] = f2bf(Wv[c * C_ + d]);
    }
}

// ---- Kernel P: fused QKV projection (MFMA). Qb/Kb: [b][n][64] bf16.
// VT: [b][c][n] bf16 (transposed V). ----
__global__ __launch_bounds__(256) void kP(const float* __restrict__ x,
                                          const ushort* __restrict__ WqT,
                                          const ushort* __restrict__ WkT,
                                          const ushort* __restrict__ WvT,
                                          ushort* __restrict__ Qb,
                                          ushort* __restrict__ Kb,
                                          ushort* __restrict__ VT) {
    __shared__ __align__(16) ushort xT[32][264];  // +8 pad breaks bank conflicts
    const int tid = threadIdx.x;
    const int b = blockIdx.x >> 7;
    const int nbase = (blockIdx.x & 127) * 32;

    // stage x^T tile: xT[n_local][c'] = x[b][c'][nbase+n_local]
    #pragma unroll
    for (int pass = 0; pass < 8; ++pass) {
        int cr = (tid >> 3) + pass * 32;
        int ns = (tid & 7) * 4;
        const f32x4 xv = *(const f32x4*)&x[(b * C_ + cr) * N_ + nbase + ns];
        #pragma unroll
        for (int j = 0; j < 4; ++j) xT[ns + j][cr] = f2bf(xv[j]);
    }
    __syncthreads();

    const int w = tid >> 6, l = tid & 63, lr = l & 15, g = l >> 4;
    f32x4 acc[2][6];
    #pragma unroll
    for (int s = 0; s < 2; ++s)
        #pragma unroll
        for (int j = 0; j < 6; ++j) acc[s][j] = (f32x4){0.f, 0.f, 0.f, 0.f};

    for (int cs = 0; cs < 8; ++cs) {
        const short8 a0 = *(const short8*)&xT[lr][cs * 32 + 8 * g];
        const short8 a1 = *(const short8*)&xT[16 + lr][cs * 32 + 8 * g];
        #pragma unroll
        for (int j = 0; j < 6; ++j) {
            const int tl = w * 6 + j;
            const ushort* src;
            if (tl < 4)      src = &WqT[(tl * 16 + lr) * C_ + cs * 32 + 8 * g];
            else if (tl < 8) src = &WkT[((tl - 4) * 16 + lr) * C_ + cs * 32 + 8 * g];
            else             src = &WvT[((tl - 8) * 16 + lr) * C_ + cs * 32 + 8 * g];
            const short8 bf = *(const short8*)src;
            acc[0][j] = __builtin_amdgcn_mfma_f32_16x16x32_bf16(a0, bf, acc[0][j], 0, 0, 0);
            acc[1][j] = __builtin_amdgcn_mfma_f32_16x16x32_bf16(a1, bf, acc[1][j], 0, 0, 0);
        }
    }

    // epilogue: C/D layout col=lane&15, row=4*(lane>>4)+r
    #pragma unroll
    for (int j = 0; j < 6; ++j) {
        const int tl = w * 6 + j;
        #pragma unroll
        for (int sub = 0; sub < 2; ++sub) {
            if (tl < 8) {
                const int dcol = (tl < 4 ? tl * 16 : (tl - 4) * 16) + lr;
                ushort* base = (tl < 4) ? Qb : Kb;
                #pragma unroll
                for (int r = 0; r < 4; ++r) {
                    int row = nbase + sub * 16 + 4 * g + r;
                    base[(b * N_ + row) * Dh + dcol] = f2bf(acc[sub][j][r]);
                }
            } else {
                const int c = (tl - 8) * 16 + lr;
                ushort4 pk;
                pk.x = f2bf(acc[sub][j][0]);
                pk.y = f2bf(acc[sub][j][1]);
                pk.z = f2bf(acc[sub][j][2]);
                pk.w = f2bf(acc[sub][j][3]);
                *(ushort4*)&VT[(b * C_ + c) * N_ + nbase + sub * 16 + 4 * g] = pk;
            }
        }
    }
}

// ---- Kernel S: column-softmax stats. m[k]=max_q s, rD[k]=gamma/sum_q exp(s-m) ----
__global__ __launch_bounds__(256) void kS(const ushort* __restrict__ Qb,
                                          const ushort* __restrict__ Kb,
                                          const float* __restrict__ gamma,
                                          float* __restrict__ mArr,
                                          float* __restrict__ rDArr) {
    const int tid = threadIdx.x;
    const int b = blockIdx.x >> 6;
    const int kbase = (blockIdx.x & 63) * 64;
    const int w = tid >> 6, l = tid & 63, lr = l & 15, g = l >> 4;
    const int kcol = kbase + w * 16 + lr;

    const short8 bk0 = *(const short8*)&Kb[(b * N_ + kcol) * Dh + 8 * g];
    const short8 bk1 = *(const short8*)&Kb[(b * N_ + kcol) * Dh + 32 + 8 * g];

    float m = -3.0e38f, d = 0.f;
    for (int it = 0; it < 256; ++it) {
        const int q = it * 16 + lr;
        const short8 a0 = *(const short8*)&Qb[(b * N_ + q) * Dh + 8 * g];
        const short8 a1 = *(const short8*)&Qb[(b * N_ + q) * Dh + 32 + 8 * g];
        f32x4 s = {0.f, 0.f, 0.f, 0.f};
        s = __builtin_amdgcn_mfma_f32_16x16x32_bf16(a0, bk0, s, 0, 0, 0);
        s = __builtin_amdgcn_mfma_f32_16x16x32_bf16(a1, bk1, s, 0, 0, 0);
        float smax = fmaxf(fmaxf(s[0], s[1]), fmaxf(s[2], s[3]));
        float nm = fmaxf(m, smax);
        d = d * __expf(m - nm)
          + __expf(s[0] - nm) + __expf(s[1] - nm)
          + __expf(s[2] - nm) + __expf(s[3] - nm);
        m = nm;
    }
    // merge the 4 row-groups (lanes l, l^16, l^32, l^48 share a column)
    #pragma unroll
    for (int off = 16; off < 64; off <<= 1) {
        float m2 = __shfl_xor(m, off, 64);
        float d2 = __shfl_xor(d, off, 64);
        float nm = fmaxf(m, m2);
        d = d * __expf(m - nm) + d2 * __expf(m2 - nm);
        m = nm;
    }
    if (l < 16) {
        mArr[b * N_ + kcol] = m;
        rDArr[b * N_ + kcol] = gamma[0] / d;
    }
}

// ---- Kernel M: main fused attention. out[b][c][n] = sum_k P[n,k]*V[k,c] + x[b][c][n] ----
__global__ __launch_bounds__(256) void kM(const ushort* __restrict__ Qb,
                                          const ushort* __restrict__ Kb,
                                          const ushort* __restrict__ VT,
                                          const float* __restrict__ mArr,
                                          const float* __restrict__ rDArr,
                                          const float* __restrict__ x,
                                          float* __restrict__ out) {
    __shared__ __align__(16) ushort P[32][72];  // +8 pad: row stride 144B
    const int tid = threadIdx.x;
    const int b = blockIdx.x >> 7;
    const int qbase = (blockIdx.x & 127) * 32;
    const int w = tid >> 6, l = tid & 63, lr = l & 15, g = l >> 4;
    const int cw = w * 64;

    short8 qf[2][2];
    #pragma unroll
    for (int qt = 0; qt < 2; ++qt)
        #pragma unroll
        for (int dt = 0; dt < 2; ++dt)
            qf[qt][dt] = *(const short8*)&Qb[(b * N_ + qbase + qt * 16 + lr) * Dh + dt * 32 + 8 * g];

    f32x4 O[2][4];
    #pragma unroll
    for (int qt = 0; qt < 2; ++qt)
        #pragma unroll
        for (int ct = 0; ct < 4; ++ct) O[qt][ct] = (f32x4){0.f, 0.f, 0.f, 0.f};

    for (int kb = 0; kb < N_; kb += 64) {
        const int kcol = kb + w * 16 + lr;
        const short8 bk0 = *(const short8*)&Kb[(b * N_ + kcol) * Dh + 8 * g];
        const short8 bk1 = *(const short8*)&Kb[(b * N_ + kcol) * Dh + 32 + 8 * g];
        f32x4 s0 = {0.f, 0.f, 0.f, 0.f}, s1 = {0.f, 0.f, 0.f, 0.f};
        s0 = __builtin_amdgcn_mfma_f32_16x16x32_bf16(qf[0][0], bk0, s0, 0, 0, 0);
        s0 = __builtin_amdgcn_mfma_f32_16x16x32_bf16(qf[0][1], bk1, s0, 0, 0, 0);
        s1 = __builtin_amdgcn_mfma_f32_16x16x32_bf16(qf[1][0], bk0, s1, 0, 0, 0);
        s1 = __builtin_amdgcn_mfma_f32_16x16x32_bf16(qf[1][1], bk1, s1, 0, 0, 0);
        const float mv = mArr[b * N_ + kcol];
        const float rd = rDArr[b * N_ + kcol];
        #pragma unroll
        for (int r = 0; r < 4; ++r) {
            P[4 * g + r][w * 16 + lr]      = f2bf(__expf(s0[r] - mv) * rd);
            P[16 + 4 * g + r][w * 16 + lr] = f2bf(__expf(s1[r] - mv) * rd);
        }
        __syncthreads();
        #pragma unroll
        for (int kt = 0; kt < 2; ++kt) {
            const short8 a0 = *(const short8*)&P[lr][kt * 32 + 8 * g];
            const short8 a1 = *(const short8*)&P[16 + lr][kt * 32 + 8 * g];
            #pragma unroll
            for (int ct = 0; ct < 4; ++ct) {
                const int c = cw + ct * 16 + lr;
                const short8 bv = *(const short8*)&VT[(b * C_ + c) * N_ + kb + kt * 32 + 8 * g];
                O[0][ct] = __builtin_amdgcn_mfma_f32_16x16x32_bf16(a0, bv, O[0][ct], 0, 0, 0);
                O[1][ct] = __builtin_amdgcn_mfma_f32_16x16x32_bf16(a1, bv, O[1][ct], 0, 0, 0);
            }
        }
        __syncthreads();
    }

    // epilogue: out[b][c][q] = O + x (residual), fused transpose
    #pragma unroll
    for (int qt = 0; qt < 2; ++qt)
        #pragma unroll
        for (int ct = 0; ct < 4; ++ct) {
            const int c = cw + ct * 16 + lr;
            const int idx = (b * C_ + c) * N_ + qbase + qt * 16 + 4 * g;
            const f32x4 xr = *(const f32x4*)&x[idx];
            f32x4 o = O[qt][ct] + xr;
            *(f32x4*)&out[idx] = o;
        }
}

extern "C" void kernel_launch(void* const* d_in, const int* in_sizes, int n_in,
                              void* d_out, int out_size, void* d_ws, size_t ws_size,
                              hipStream_t stream) {
    const float* x     = (const float*)d_in[0];
    const float* Wq    = (const float*)d_in[1];
    const float* Wk    = (const float*)d_in[2];
    const float* Wv    = (const float*)d_in[3];
    const float* gamma = (const float*)d_in[4];
    float* out = (float*)d_out;

    ushort* Qb  = (ushort*)d_ws;                 // 4*4096*64  bf16 (2 MB)
    ushort* Kb  = Qb + B_ * N_ * Dh;             // 2 MB
    ushort* VT  = Kb + B_ * N_ * Dh;             // 4*256*4096 bf16 (8 MB)
    ushort* WqT = VT + B_ * C_ * N_;             // 32 KB
    ushort* WkT = WqT + Dh * C_;                 // 32 KB
    ushort* WvT = WkT + Dh * C_;                 // 128 KB
    float*  mArr  = (float*)(WvT + C_ * C_);     // 64 KB
    float*  rDArr = mArr + B_ * N_;              // 64 KB

    kT<<<256, 256, 0, stream>>>(Wq, Wk, Wv, WqT, WkT, WvT);
    kP<<<512, 256, 0, stream>>>(x, WqT, WkT, WvT, Qb, Kb, VT);
    kS<<<256, 256, 0, stream>>>(Qb, Kb, gamma, mArr, rDArr);
    kM<<<512, 256, 0, stream>>>(Qb, Kb, VT, mArr, rDArr, x, out);
}

// Round 5
// 241.670 us; speedup vs baseline: 1.3470x; 1.3470x over previous
//
#include <hip/hip_runtime.h>
#include <hip/hip_bf16.h>

#define B_ 4
#define C_ 256
#define N_ 4096
#define Dh 64

typedef __attribute__((ext_vector_type(8))) short short8;
typedef __attribute__((ext_vector_type(4))) float f32x4;

__device__ __forceinline__ ushort f2bf(float f) {
    union { float f; unsigned u; } v; v.f = f;
    unsigned u = v.u;
    return (ushort)((u + 0x7fffu + ((u >> 16) & 1u)) >> 16);
}

// ---- Kernel T: weights -> bf16, transposed (WT[d][c] = W[c][d]) ----
__global__ __launch_bounds__(256) void kT(const float* __restrict__ Wq,
                                          const float* __restrict__ Wk,
                                          const float* __restrict__ Wv,
                                          ushort* __restrict__ WqT,
                                          ushort* __restrict__ WkT,
                                          ushort* __restrict__ WvT) {
    int i = blockIdx.x * 256 + threadIdx.x;
    if (i < Dh * C_) {
        int d = i / C_, c = i % C_;
        WqT[i] = f2bf(Wq[c * Dh + d]);
        WkT[i] = f2bf(Wk[c * Dh + d]);
    }
    if (i < C_ * C_) {
        int d = i / C_, c = i % C_;
        WvT[i] = f2bf(Wv[c * C_ + d]);
    }
}

// ---- Kernel P: fused QKV projection (MFMA). Qb/Kb: [b][n][64] bf16.
// VT: [b][c][n] bf16 (transposed V). ----
__global__ __launch_bounds__(256) void kP(const float* __restrict__ x,
                                          const ushort* __restrict__ WqT,
                                          const ushort* __restrict__ WkT,
                                          const ushort* __restrict__ WvT,
                                          ushort* __restrict__ Qb,
                                          ushort* __restrict__ Kb,
                                          ushort* __restrict__ VT) {
    __shared__ __align__(16) ushort xT[32][264];
    const int tid = threadIdx.x;
    const int b = blockIdx.x >> 7;
    const int nbase = (blockIdx.x & 127) * 32;

    #pragma unroll
    for (int pass = 0; pass < 8; ++pass) {
        int cr = (tid >> 3) + pass * 32;
        int ns = (tid & 7) * 4;
        const f32x4 xv = *(const f32x4*)&x[(b * C_ + cr) * N_ + nbase + ns];
        #pragma unroll
        for (int j = 0; j < 4; ++j) xT[ns + j][cr] = f2bf(xv[j]);
    }
    __syncthreads();

    const int w = tid >> 6, l = tid & 63, lr = l & 15, g = l >> 4;
    f32x4 acc[2][6];
    #pragma unroll
    for (int s = 0; s < 2; ++s)
        #pragma unroll
        for (int j = 0; j < 6; ++j) acc[s][j] = (f32x4){0.f, 0.f, 0.f, 0.f};

    for (int cs = 0; cs < 8; ++cs) {
        const short8 a0 = *(const short8*)&xT[lr][cs * 32 + 8 * g];
        const short8 a1 = *(const short8*)&xT[16 + lr][cs * 32 + 8 * g];
        #pragma unroll
        for (int j = 0; j < 6; ++j) {
            const int tl = w * 6 + j;
            const ushort* src;
            if (tl < 4)      src = &WqT[(tl * 16 + lr) * C_ + cs * 32 + 8 * g];
            else if (tl < 8) src = &WkT[((tl - 4) * 16 + lr) * C_ + cs * 32 + 8 * g];
            else             src = &WvT[((tl - 8) * 16 + lr) * C_ + cs * 32 + 8 * g];
            const short8 bf = *(const short8*)src;
            acc[0][j] = __builtin_amdgcn_mfma_f32_16x16x32_bf16(a0, bf, acc[0][j], 0, 0, 0);
            acc[1][j] = __builtin_amdgcn_mfma_f32_16x16x32_bf16(a1, bf, acc[1][j], 0, 0, 0);
        }
    }

    #pragma unroll
    for (int j = 0; j < 6; ++j) {
        const int tl = w * 6 + j;
        #pragma unroll
        for (int sub = 0; sub < 2; ++sub) {
            if (tl < 8) {
                const int dcol = (tl < 4 ? tl * 16 : (tl - 4) * 16) + lr;
                ushort* base = (tl < 4) ? Qb : Kb;
                #pragma unroll
                for (int r = 0; r < 4; ++r) {
                    int row = nbase + sub * 16 + 4 * g + r;
                    base[(b * N_ + row) * Dh + dcol] = f2bf(acc[sub][j][r]);
                }
            } else {
                const int c = (tl - 8) * 16 + lr;
                ushort4 pk;
                pk.x = f2bf(acc[sub][j][0]);
                pk.y = f2bf(acc[sub][j][1]);
                pk.z = f2bf(acc[sub][j][2]);
                pk.w = f2bf(acc[sub][j][3]);
                *(ushort4*)&VT[(b * C_ + c) * N_ + nbase + sub * 16 + 4 * g] = pk;
            }
        }
    }
}

// ---- Kernel S1: partial column-softmax stats over a 512-q chunk ----
__global__ __launch_bounds__(256) void kS1(const ushort* __restrict__ Qb,
                                           const ushort* __restrict__ Kb,
                                           float* __restrict__ mPart,
                                           float* __restrict__ dPart) {
    const int tid = threadIdx.x;
    const int orig = blockIdx.x;                  // 2048 blocks
    const int b = (orig & 7) >> 1;                // batch pinned to XCD pair
    const int sub = ((orig >> 3) << 1) | (orig & 1);   // 0..511
    const int kblk = sub & 63;
    const int qs = sub >> 6;                      // 0..7
    const int w = tid >> 6, l = tid & 63, lr = l & 15, g = l >> 4;
    const int kcol = kblk * 64 + w * 16 + lr;

    const short8 bk0 = *(const short8*)&Kb[(b * N_ + kcol) * Dh + 8 * g];
    const short8 bk1 = *(const short8*)&Kb[(b * N_ + kcol) * Dh + 32 + 8 * g];

    float m = -3.0e38f, d = 0.f;
    for (int it = 0; it < 32; ++it) {
        const int q = qs * 512 + it * 16 + lr;
        const short8 a0 = *(const short8*)&Qb[(b * N_ + q) * Dh + 8 * g];
        const short8 a1 = *(const short8*)&Qb[(b * N_ + q) * Dh + 32 + 8 * g];
        f32x4 s = {0.f, 0.f, 0.f, 0.f};
        s = __builtin_amdgcn_mfma_f32_16x16x32_bf16(a0, bk0, s, 0, 0, 0);
        s = __builtin_amdgcn_mfma_f32_16x16x32_bf16(a1, bk1, s, 0, 0, 0);
        float smax = fmaxf(fmaxf(s[0], s[1]), fmaxf(s[2], s[3]));
        if (smax > m) { d *= __expf(m - smax); m = smax; }   // defer-max: rare path
        d += __expf(s[0] - m) + __expf(s[1] - m)
           + __expf(s[2] - m) + __expf(s[3] - m);
    }
    #pragma unroll
    for (int off = 16; off < 64; off <<= 1) {
        float m2 = __shfl_xor(m, off, 64);
        float d2 = __shfl_xor(d, off, 64);
        float nm = fmaxf(m, m2);
        d = d * __expf(m - nm) + d2 * __expf(m2 - nm);
        m = nm;
    }
    if (l < 16) {
        mPart[((b << 3) + qs) * N_ + kcol] = m;
        dPart[((b << 3) + qs) * N_ + kcol] = d;
    }
}

// ---- Kernel S2: merge 8 partials -> m, gamma/D ----
__global__ __launch_bounds__(256) void kS2(const float* __restrict__ mPart,
                                           const float* __restrict__ dPart,
                                           const float* __restrict__ gamma,
                                           float* __restrict__ mArr,
                                           float* __restrict__ rDArr) {
    const int i = blockIdx.x * 256 + threadIdx.x;   // [0, B*N)
    const int b = i >> 12, k = i & (N_ - 1);
    float m = -3.0e38f, d = 0.f;
    #pragma unroll
    for (int qs = 0; qs < 8; ++qs) {
        float mq = mPart[((b << 3) + qs) * N_ + k];
        float dq = dPart[((b << 3) + qs) * N_ + k];
        float nm = fmaxf(m, mq);
        d = d * __expf(m - nm) + dq * __expf(mq - nm);
        m = nm;
    }
    mArr[i] = m;
    rDArr[i] = gamma[0] / d;
}

// ---- Kernel M: fused attention. 512 thr, Q-tile 32, K-tile 256, dbuf P ----
__global__ __launch_bounds__(512, 4) void kM(const ushort* __restrict__ Qb,
                                             const ushort* __restrict__ Kb,
                                             const ushort* __restrict__ VT,
                                             const float* __restrict__ mArr,
                                             const float* __restrict__ rDArr,
                                             const float* __restrict__ x,
                                             float* __restrict__ out) {
    __shared__ __align__(16) ushort P[2][32][264];
    const int tid = threadIdx.x;
    const int orig = blockIdx.x;                  // 512 blocks
    const int b = (orig & 7) >> 1;                // batch pinned to XCD pair -> L2 reuse
    const int qblk = ((orig >> 3) << 1) | (orig & 1);
    const int qbase = qblk * 32;
    const int w = tid >> 6, l = tid & 63, lr = l & 15, g = l >> 4;

    short8 qf[2][2];
    #pragma unroll
    for (int qt = 0; qt < 2; ++qt)
        #pragma unroll
        for (int dt = 0; dt < 2; ++dt)
            qf[qt][dt] = *(const short8*)&Qb[(b * N_ + qbase + qt * 16 + lr) * Dh + dt * 32 + 8 * g];

    f32x4 O[2][2];
    #pragma unroll
    for (int qt = 0; qt < 2; ++qt)
        #pragma unroll
        for (int ct = 0; ct < 2; ++ct) O[qt][ct] = (f32x4){0.f, 0.f, 0.f, 0.f};

    #pragma unroll 2
    for (int it = 0; it < 16; ++it) {
        const int kb = it << 8;
        ushort (*Pb)[264] = P[it & 1];
        // ---- S phase: this wave computes S[32 q][k = kb+w*32 .. +32) ----
        #pragma unroll
        for (int j = 0; j < 2; ++j) {
            const int kcol = kb + w * 32 + j * 16 + lr;
            const short8 bk0 = *(const short8*)&Kb[(b * N_ + kcol) * Dh + 8 * g];
            const short8 bk1 = *(const short8*)&Kb[(b * N_ + kcol) * Dh + 32 + 8 * g];
            const float mv = mArr[b * N_ + kcol];
            const float rd = rDArr[b * N_ + kcol];
            const int colbase = (w * 32 + j * 16 + lr) ^ (g << 3);  // XOR-swizzle, row>>2&3 == g
            #pragma unroll
            for (int qt = 0; qt < 2; ++qt) {
                f32x4 s = {0.f, 0.f, 0.f, 0.f};
                s = __builtin_amdgcn_mfma_f32_16x16x32_bf16(qf[qt][0], bk0, s, 0, 0, 0);
                s = __builtin_amdgcn_mfma_f32_16x16x32_bf16(qf[qt][1], bk1, s, 0, 0, 0);
                #pragma unroll
                for (int r = 0; r < 4; ++r)
                    Pb[qt * 16 + 4 * g + r][colbase] = f2bf(__expf(s[r] - mv) * rd);
            }
        }
        __syncthreads();
        // ---- PV phase: this wave owns channels c = w*32 .. +32 ----
        #pragma unroll
        for (int kt = 0; kt < 8; ++kt) {
            short8 pa[2];
            #pragma unroll
            for (int qt = 0; qt < 2; ++qt)
                pa[qt] = *(const short8*)&Pb[qt * 16 + lr][(kt * 32 + 8 * g) ^ ((lr & 12) << 1)];
            #pragma unroll
            for (int ct = 0; ct < 2; ++ct) {
                const int c = w * 32 + ct * 16 + lr;
                const short8 bv = *(const short8*)&VT[(b * C_ + c) * N_ + kb + kt * 32 + 8 * g];
                O[0][ct] = __builtin_amdgcn_mfma_f32_16x16x32_bf16(pa[0], bv, O[0][ct], 0, 0, 0);
                O[1][ct] = __builtin_amdgcn_mfma_f32_16x16x32_bf16(pa[1], bv, O[1][ct], 0, 0, 0);
            }
        }
        // no second barrier: double-buffered P
    }

    #pragma unroll
    for (int qt = 0; qt < 2; ++qt)
        #pragma unroll
        for (int ct = 0; ct < 2; ++ct) {
            const int c = w * 32 + ct * 16 + lr;
            const int idx = (b * C_ + c) * N_ + qbase + qt * 16 + 4 * g;
            const f32x4 xr = *(const f32x4*)&x[idx];
            f32x4 o = O[qt][ct] + xr;
            *(f32x4*)&out[idx] = o;
        }
}

extern "C" void kernel_launch(void* const* d_in, const int* in_sizes, int n_in,
                              void* d_out, int out_size, void* d_ws, size_t ws_size,
                              hipStream_t stream) {
    const float* x     = (const float*)d_in[0];
    const float* Wq    = (const float*)d_in[1];
    const float* Wk    = (const float*)d_in[2];
    const float* Wv    = (const float*)d_in[3];
    const float* gamma = (const float*)d_in[4];
    float* out = (float*)d_out;

    ushort* Qb  = (ushort*)d_ws;                 // 2 MB
    ushort* Kb  = Qb + B_ * N_ * Dh;             // 2 MB
    ushort* VT  = Kb + B_ * N_ * Dh;             // 8 MB
    ushort* WqT = VT + B_ * C_ * N_;             // 32 KB
    ushort* WkT = WqT + Dh * C_;                 // 32 KB
    ushort* WvT = WkT + Dh * C_;                 // 128 KB
    float*  mArr  = (float*)(WvT + C_ * C_);     // 64 KB
    float*  rDArr = mArr + B_ * N_;              // 64 KB
    float*  mPart = rDArr + B_ * N_;             // 512 KB
    float*  dPart = mPart + 8 * B_ * N_;         // 512 KB

    kT<<<256, 256, 0, stream>>>(Wq, Wk, Wv, WqT, WkT, WvT);
    kP<<<512, 256, 0, stream>>>(x, WqT, WkT, WvT, Qb, Kb, VT);
    kS1<<<2048, 256, 0, stream>>>(Qb, Kb, mPart, dPart);
    kS2<<<64, 256, 0, stream>>>(mPart, dPart, gamma, mArr, rDArr);
    kM<<<512, 512, 0, stream>>>(Qb, Kb, VT, mArr, rDArr, x, out);
}